// Round 2
// baseline (213.421 us; speedup 1.0000x reference)
//
#include <hip/hip_runtime.h>

#define WIN 33
#define WIDTH 128
#define MPTS 64
#define NN 2048
#define MM 2048
#define DD 64
#define NQ 2080   // N + 2L

typedef __bf16 bf16x8 __attribute__((ext_vector_type(8)));
typedef float f32x4 __attribute__((ext_vector_type(4)));

__device__ __forceinline__ unsigned short f2bf(float x) {
  union { float f; unsigned int u; } v; v.f = x;
  unsigned int r = v.u + 0x7FFFu + ((v.u >> 16) & 1u);  // RNE
  return (unsigned short)(r >> 16);
}
__device__ __forceinline__ float sigf(float x) { return 1.0f / (1.0f + __expf(-x)); }

// ------------- xi[M][NQ] f32  ->  xiT[NQ][M] bf16 (transpose + convert) ----
// 64m x 32q tile per block; float4 global reads, ushort4 global writes.
__global__ __launch_bounds__(256) void k_transpose(const float* __restrict__ xi,
                                                   unsigned short* __restrict__ xiT) {
  __shared__ float ts[64 * 37];            // [m][q], stride 37 breaks conflicts
  int qb = blockIdx.x * 32;                // 65 tiles over NQ=2080
  int mb = blockIdx.y * 64;                // 32 tiles over M=2048
#pragma unroll
  for (int c = threadIdx.x; c < 512; c += 256) {   // 64 rows x 8 float4
    int row = c >> 3, c8 = c & 7;
    float4 v = *(const float4*)&xi[(size_t)(mb + row) * NQ + qb + (c8 << 2)];
    ts[row * 37 + (c8 << 2) + 0] = v.x;
    ts[row * 37 + (c8 << 2) + 1] = v.y;
    ts[row * 37 + (c8 << 2) + 2] = v.z;
    ts[row * 37 + (c8 << 2) + 3] = v.w;
  }
  __syncthreads();
#pragma unroll
  for (int c = threadIdx.x; c < 512; c += 256) {   // 32 q-rows x 16 m-quads
    int r = c >> 4, mq = c & 15;
    ushort4 h;
    h.x = f2bf(ts[(mq * 4 + 0) * 37 + r]);
    h.y = f2bf(ts[(mq * 4 + 1) * 37 + r]);
    h.z = f2bf(ts[(mq * 4 + 2) * 37 + r]);
    h.w = f2bf(ts[(mq * 4 + 3) * 37 + r]);
    *(ushort4*)&xiT[(size_t)(qb + r) * MM + mb + (mq << 2)] = h;
  }
}

// ------------- layer0: u1[j][k][p] = sig(dot64(w0[j][k], u[p]) + b0) -------
__global__ __launch_bounds__(256) void k_layer0(const float* __restrict__ u,
                                                const float* __restrict__ w0,
                                                const float* __restrict__ b0,
                                                float* __restrict__ out) {
  int b = blockIdx.x;                      // 33*32 blocks
  int j = b >> 5;
  int k = ((b & 31) << 2) + (threadIdx.x >> 6);
  int p = threadIdx.x & 63;
  const float* wr = w0 + (size_t)(j * WIDTH + k) * DD;
  const float* ur = u + (size_t)p * DD;
  float a0 = 0.f, a1 = 0.f;
#pragma unroll
  for (int l = 0; l < DD; l += 8) {
    float4 w0v = *(const float4*)(wr + l);
    float4 u0v = *(const float4*)(ur + l);
    float4 w1v = *(const float4*)(wr + l + 4);
    float4 u1v = *(const float4*)(ur + l + 4);
    a0 += w0v.x * u0v.x + w0v.y * u0v.y + w0v.z * u0v.z + w0v.w * u0v.w;
    a1 += w1v.x * u1v.x + w1v.y * u1v.y + w1v.z * u1v.z + w1v.w * u1v.w;
  }
  out[(size_t)(j * WIDTH + k) * MPTS + p] = sigf(a0 + a1 + b0[j * WIDTH + k]);
}

// ------------- hidden layer: u1'[j][k][p] = sig(dot128(w[j][k], u1[j][:][p]))
// last=0: write fp32 [j][k][p]   last=1: write bf16 transposed [j][p][k] -----
__global__ __launch_bounds__(256) void k_layer_mid(const float* __restrict__ w,
                                                   const float* __restrict__ bias,
                                                   const float* __restrict__ in,
                                                   float* __restrict__ outf,
                                                   unsigned short* __restrict__ outbf,
                                                   int last) {
  int b = blockIdx.x;                      // 33*32 blocks
  int j = b >> 5;
  int k = ((b & 31) << 2) + (threadIdx.x >> 6);
  int p = threadIdx.x & 63;
  const float* wr = w + (size_t)(j * WIDTH + k) * WIDTH;
  const float* ip = in + (size_t)j * WIDTH * MPTS + p;
  float a0 = 0.f, a1 = 0.f, a2 = 0.f, a3 = 0.f;
#pragma unroll 8
  for (int l = 0; l < WIDTH; l += 4) {
    float4 wv = *(const float4*)(wr + l);
    a0 += wv.x * ip[(size_t)(l + 0) * MPTS];
    a1 += wv.y * ip[(size_t)(l + 1) * MPTS];
    a2 += wv.z * ip[(size_t)(l + 2) * MPTS];
    a3 += wv.w * ip[(size_t)(l + 3) * MPTS];
  }
  float s = sigf((a0 + a1) + (a2 + a3) + bias[j * WIDTH + k]);
  if (last) outbf[(size_t)(j * MPTS + p) * WIDTH + k] = f2bf(s);
  else      outf[(size_t)(j * WIDTH + k) * MPTS + p] = s;
}

// ------------- phase B: Gt2[j][p][m] = sig(dot128(wf[m][j], u1[j][:, p]) + bfin)
// grid = 33 j x 32 m-tiles(64); block C-tile 64m x 64p, K=128 ---------------
__global__ __launch_bounds__(256) void k_final(const float* __restrict__ wf,
                                               const float* __restrict__ bfin,
                                               const unsigned short* __restrict__ u1bf,
                                               unsigned short* __restrict__ Gt2) {
  constexpr int KP = 136;                  // 128 + 8 pad
  __shared__ unsigned short As[64 * KP];   // wf tile [m][k] bf16
  __shared__ unsigned short Bs[64 * KP];   // u1 [p][k] bf16
  int bid = blockIdx.x;                    // 33*32
  int j = bid >> 5;
  int m0 = (bid & 31) << 6;
#pragma unroll
  for (int c = threadIdx.x; c < 64 * 32; c += 256) {
    int row = c >> 5, f4 = c & 31;
    float4 v = *(const float4*)(wf + ((size_t)(m0 + row) * WIN + j) * WIDTH + (f4 << 2));
    ushort4 h;
    h.x = f2bf(v.x); h.y = f2bf(v.y); h.z = f2bf(v.z); h.w = f2bf(v.w);
    *(ushort4*)(&As[row * KP + (f4 << 2)]) = h;
  }
#pragma unroll
  for (int c = threadIdx.x; c < 64 * 16; c += 256) {
    int p = c >> 4, ch = c & 15;
    uint4 v = *(const uint4*)(u1bf + (size_t)(j * MPTS + p) * WIDTH + (ch << 3));
    *(uint4*)(&Bs[p * KP + (ch << 3)]) = v;
  }
  __syncthreads();
  int wv = threadIdx.x >> 6, lane = threadIdx.x & 63;
  int l15 = lane & 15, l4 = lane >> 4;
  f32x4 acc[4] = {};
#pragma unroll
  for (int t = 0; t < 4; ++t) {
    int col = (t << 5) + (l4 << 3);
    bf16x8 a = *(const bf16x8*)(&As[(wv * 16 + l15) * KP + col]);
#pragma unroll
    for (int q = 0; q < 4; ++q) {
      bf16x8 bb = *(const bf16x8*)(&Bs[(q * 16 + l15) * KP + col]);
      acc[q] = __builtin_amdgcn_mfma_f32_16x16x32_bf16(a, bb, acc[q], 0, 0, 0);
    }
  }
#pragma unroll
  for (int q = 0; q < 4; ++q) {
    int mr = m0 + wv * 16 + (l4 << 2);     // 4 consecutive m per lane
    int p = q * 16 + l15;
    float z0 = acc[q][0] + bfin[(size_t)(mr + 0) * WIN + j];
    float z1 = acc[q][1] + bfin[(size_t)(mr + 1) * WIN + j];
    float z2 = acc[q][2] + bfin[(size_t)(mr + 2) * WIN + j];
    float z3 = acc[q][3] + bfin[(size_t)(mr + 3) * WIN + j];
    ushort4 st;
    st.x = f2bf(sigf(z0)); st.y = f2bf(sigf(z1));
    st.z = f2bf(sigf(z2)); st.w = f2bf(sigf(z3));
    *(ushort4*)(&Gt2[(size_t)(j * MPTS + p) * MM + mr]) = st;
  }
}

// ------------- phase C: out[n,p] += sum_{j,m} xiT[n+j,m] * Gt2[j,p,m] ------
// grid 512 = 8 n-tiles(256) x 64 m-chunks(32). Block 4 waves, wave 64n x 64p.
// Ping-pong Bs + register prefetch: one barrier per j, latency hidden. ------
__global__ __launch_bounds__(256) void k_conv(const unsigned short* __restrict__ xiT,
                                              const unsigned short* __restrict__ Gt2,
                                              float* __restrict__ out) {
  constexpr int AP = 40;                   // 32 + 8 pad (2-way bank alias = free)
  __shared__ unsigned short As[288 * AP];  // xiT rows n0..n0+287, 32 m
  __shared__ unsigned short Bs[2][64 * AP];// Gt2[j] 64p x 32m, ping-pong
  int bid = blockIdx.x;
  int n0 = (bid & 7) << 8;                 // 8 n-tiles of 256
  int m0 = (bid >> 3) << 5;                // 64 m-chunks of 32
  // stage A once: 288 rows x 4 uint4
  for (int c = threadIdx.x; c < 288 * 4; c += 256) {
    int row = c >> 2, mq = c & 3;
    uint4 v = *(const uint4*)(xiT + (size_t)(n0 + row) * MM + m0 + (mq << 3));
    *(uint4*)(&As[row * AP + (mq << 3)]) = v;
  }
  int wv = threadIdx.x >> 6, lane = threadIdx.x & 63;
  int l15 = lane & 15, l4 = lane >> 4;
  int sp = threadIdx.x >> 2, smq = threadIdx.x & 3;   // B staging coords
  const unsigned short* gB = Gt2 + (size_t)sp * MM + m0 + (smq << 3);
  f32x4 acc[4][4] = {};
  uint4 breg = *(const uint4*)gB;          // prefetch j=0
  for (int j = 0; j < WIN; ++j) {
    *(uint4*)(&Bs[j & 1][sp * AP + (smq << 3)]) = breg;
    __syncthreads();                        // j=0 also covers A staging
    if (j + 1 < WIN)
      breg = *(const uint4*)(gB + (size_t)(j + 1) * MPTS * MM);
    const unsigned short* Bb = &Bs[j & 1][0];
    bf16x8 a[4], bb[4];
#pragma unroll
    for (int s = 0; s < 4; ++s)
      a[s] = *(const bf16x8*)(&As[(wv * 64 + s * 16 + l15 + j) * AP + (l4 << 3)]);
#pragma unroll
    for (int q = 0; q < 4; ++q)
      bb[q] = *(const bf16x8*)(&Bb[(q * 16 + l15) * AP + (l4 << 3)]);
#pragma unroll
    for (int s = 0; s < 4; ++s)
#pragma unroll
      for (int q = 0; q < 4; ++q)
        acc[s][q] = __builtin_amdgcn_mfma_f32_16x16x32_bf16(a[s], bb[q], acc[s][q], 0, 0, 0);
  }
#pragma unroll
  for (int s = 0; s < 4; ++s)
#pragma unroll
    for (int q = 0; q < 4; ++q) {
      int nr = n0 + wv * 64 + s * 16 + (l4 << 2);
      int p = q * 16 + l15;
#pragma unroll
      for (int i = 0; i < 4; ++i)
        atomicAdd(&out[(size_t)(nr + i) * MPTS + p], acc[s][q][i]);
    }
}

extern "C" void kernel_launch(void* const* d_in, const int* in_sizes, int n_in,
                              void* d_out, int out_size, void* d_ws, size_t ws_size,
                              hipStream_t stream) {
  const float* u    = (const float*)d_in[0];  // [64,64]
  const float* w0   = (const float*)d_in[1];  // [33,128,64]
  const float* b0   = (const float*)d_in[2];  // [33,128,1]
  const float* w    = (const float*)d_in[3];  // [2,33,128,128]
  const float* bias = (const float*)d_in[4];  // [2,33,128,1]
  const float* wf   = (const float*)d_in[5];  // [2048,33,128]
  const float* bfin = (const float*)d_in[6];  // [2048,33,1]
  const float* xi   = (const float*)d_in[7];  // [2048,2080]
  float* out = (float*)d_out;                 // [2048,64]
  char* ws = (char*)d_ws;
  unsigned short* xiT  = (unsigned short*)(ws);             // 2080*2048*2   = 8,519,680
  unsigned short* Gt2  = (unsigned short*)(ws + 8519680);   // 33*64*2048*2  = 8,650,752
  float*          u1a  = (float*)(ws + 17170432);           // 33*128*64*4   = 1,081,344
  float*          u1b  = (float*)(ws + 18251776);           // 1,081,344
  unsigned short* u1bf = (unsigned short*)(ws + 19333120);  // 33*64*128*2   = 540,672

  hipMemsetAsync(out, 0, (size_t)out_size * sizeof(float), stream);
  k_transpose<<<dim3(65, 32), 256, 0, stream>>>(xi, xiT);
  k_layer0<<<33 * 32, 256, 0, stream>>>(u, w0, b0, u1a);
  k_layer_mid<<<33 * 32, 256, 0, stream>>>(w, bias, u1a, u1b, (unsigned short*)nullptr, 0);
  k_layer_mid<<<33 * 32, 256, 0, stream>>>(w + (size_t)WIN * WIDTH * WIDTH,
                                           bias + (size_t)WIN * WIDTH,
                                           u1b, (float*)nullptr, u1bf, 1);
  k_final<<<33 * 32, 256, 0, stream>>>(wf, bfin, u1bf, Gt2);
  k_conv<<<512, 256, 0, stream>>>(xiT, Gt2, out);
}

// Round 4
// 185.242 us; speedup vs baseline: 1.1521x; 1.1521x over previous
//
#include <hip/hip_runtime.h>

#define WIN 33
#define WIDTH 128
#define MPTS 64
#define NN 2048
#define MM 2048
#define DD 64
#define NQ 2080   // N + 2L

typedef __bf16 bf16x8 __attribute__((ext_vector_type(8)));
typedef float f32x4 __attribute__((ext_vector_type(4)));

__device__ __forceinline__ unsigned short f2bf(float x) {
  union { float f; unsigned int u; } v; v.f = x;
  unsigned int r = v.u + 0x7FFFu + ((v.u >> 16) & 1u);  // RNE
  return (unsigned short)(r >> 16);
}
__device__ __forceinline__ float sigf(float x) { return 1.0f / (1.0f + __expf(-x)); }

// ------------- xi[M][NQ] f32  ->  xiT[NQ][M] bf16 (transpose + convert) ----
__global__ __launch_bounds__(256) void k_transpose(const float* __restrict__ xi,
                                                   unsigned short* __restrict__ xiT) {
  __shared__ float ts[64 * 37];
  int qb = blockIdx.x * 32;                // 65 tiles over NQ=2080
  int mb = blockIdx.y * 64;                // 32 tiles over M=2048
#pragma unroll
  for (int c = threadIdx.x; c < 512; c += 256) {   // 64 rows x 8 float4
    int row = c >> 3, c8 = c & 7;
    float4 v = *(const float4*)&xi[(size_t)(mb + row) * NQ + qb + (c8 << 2)];
    ts[row * 37 + (c8 << 2) + 0] = v.x;
    ts[row * 37 + (c8 << 2) + 1] = v.y;
    ts[row * 37 + (c8 << 2) + 2] = v.z;
    ts[row * 37 + (c8 << 2) + 3] = v.w;
  }
  __syncthreads();
#pragma unroll
  for (int c = threadIdx.x; c < 512; c += 256) {   // 32 q-rows x 16 m-quads
    int r = c >> 4, mq = c & 15;
    ushort4 h;
    h.x = f2bf(ts[(mq * 4 + 0) * 37 + r]);
    h.y = f2bf(ts[(mq * 4 + 1) * 37 + r]);
    h.z = f2bf(ts[(mq * 4 + 2) * 37 + r]);
    h.w = f2bf(ts[(mq * 4 + 3) * 37 + r]);
    *(ushort4*)&xiT[(size_t)(qb + r) * MM + mb + (mq << 2)] = h;
  }
}

// ------------- fused 3-layer MLP, one block per j -------------------------
// u1bf[j][p][k] = sig(L2(sig(L1(sig(L0)))))  via MFMA, LDS-resident acts.
__global__ __launch_bounds__(256) void k_mlp(const float* __restrict__ u,
                                             const float* __restrict__ w0,
                                             const float* __restrict__ b0,
                                             const float* __restrict__ w,
                                             const float* __restrict__ bias,
                                             unsigned short* __restrict__ u1bf) {
  constexpr int WS = 72;                   // weight row stride (shorts)
  constexpr int AS = 136;                  // act row stride (shorts)
  __shared__ unsigned short ws[128 * WS];  // weight tile [k][d] bf16
  __shared__ unsigned short actA[64 * AS]; // activations [p][k] bf16
  __shared__ unsigned short actB[64 * AS];
  __shared__ float biass[128];
  int j = blockIdx.x;
  int tid = threadIdx.x;
  int wv = tid >> 6, lane = tid & 63, l15 = lane & 15, l4 = lane >> 4;

  // stage u -> actA[p][d]  (64 x 64)
#pragma unroll
  for (int c = tid; c < 1024; c += 256) {
    int p = c >> 4, d4 = (c & 15) << 2;
    float4 v = *(const float4*)&u[(size_t)p * DD + d4];
    ushort4 h; h.x = f2bf(v.x); h.y = f2bf(v.y); h.z = f2bf(v.z); h.w = f2bf(v.w);
    *(ushort4*)&actA[p * AS + d4] = h;
  }
  // stage w0[j] -> ws[k][d] (128 x 64)
#pragma unroll
  for (int c = tid; c < 2048; c += 256) {
    int k = c >> 4, d4 = (c & 15) << 2;
    float4 v = *(const float4*)&w0[((size_t)j * 128 + k) * DD + d4];
    ushort4 h; h.x = f2bf(v.x); h.y = f2bf(v.y); h.z = f2bf(v.z); h.w = f2bf(v.w);
    *(ushort4*)&ws[k * WS + d4] = h;
  }
  if (tid < 128) biass[tid] = b0[j * 128 + tid];
  __syncthreads();

  // ---- layer 0: K=64, in actA, out actB ----
  {
    f32x4 acc[2][4] = {};
#pragma unroll
    for (int t = 0; t < 2; ++t) {
      int col = (t << 5) + (l4 << 3);
      bf16x8 a[2], b[4];
#pragma unroll
      for (int s = 0; s < 2; ++s)
        a[s] = *(const bf16x8*)&ws[(wv * 32 + s * 16 + l15) * WS + col];
#pragma unroll
      for (int q = 0; q < 4; ++q)
        b[q] = *(const bf16x8*)&actA[(q * 16 + l15) * AS + col];
#pragma unroll
      for (int s = 0; s < 2; ++s)
#pragma unroll
        for (int q = 0; q < 4; ++q)
          acc[s][q] = __builtin_amdgcn_mfma_f32_16x16x32_bf16(a[s], b[q], acc[s][q], 0, 0, 0);
    }
#pragma unroll
    for (int s = 0; s < 2; ++s)
#pragma unroll
      for (int q = 0; q < 4; ++q) {
        int p = q * 16 + l15;
#pragma unroll
        for (int r = 0; r < 4; ++r) {
          int k = wv * 32 + s * 16 + (l4 << 2) + r;
          actB[p * AS + k] = f2bf(sigf(acc[s][q][r] + biass[k]));
        }
      }
  }

  // ---- hidden layers i=0,1: K=128 in two halves ----
  unsigned short* ain = actB;
  unsigned short* aout = actA;
#pragma unroll
  for (int i = 0; i < 2; ++i) {
    f32x4 acc[2][4] = {};
    const float* wbase = w + ((size_t)i * WIN + j) * 128 * 128;
#pragma unroll
    for (int h = 0; h < 2; ++h) {
      __syncthreads();   // all reads of ws/biass from previous stage done
#pragma unroll
      for (int c = tid; c < 2048; c += 256) {
        int k = c >> 4, d4 = (c & 15) << 2;
        float4 v = *(const float4*)&wbase[(size_t)k * 128 + h * 64 + d4];
        ushort4 hh; hh.x = f2bf(v.x); hh.y = f2bf(v.y); hh.z = f2bf(v.z); hh.w = f2bf(v.w);
        *(ushort4*)&ws[k * WS + d4] = hh;
      }
      if (h == 0 && tid < 128) biass[tid] = bias[((size_t)i * WIN + j) * 128 + tid];
      __syncthreads();
#pragma unroll
      for (int t = 0; t < 2; ++t) {
        int col = (t << 5) + (l4 << 3);
        bf16x8 a[2], b[4];
#pragma unroll
        for (int s = 0; s < 2; ++s)
          a[s] = *(const bf16x8*)&ws[(wv * 32 + s * 16 + l15) * WS + col];
#pragma unroll
        for (int q = 0; q < 4; ++q)
          b[q] = *(const bf16x8*)&ain[(q * 16 + l15) * AS + h * 64 + col];
#pragma unroll
        for (int s = 0; s < 2; ++s)
#pragma unroll
          for (int q = 0; q < 4; ++q)
            acc[s][q] = __builtin_amdgcn_mfma_f32_16x16x32_bf16(a[s], b[q], acc[s][q], 0, 0, 0);
      }
    }
#pragma unroll
    for (int s = 0; s < 2; ++s)
#pragma unroll
      for (int q = 0; q < 4; ++q) {
        int p = q * 16 + l15;
#pragma unroll
        for (int r = 0; r < 4; ++r) {
          int k = wv * 32 + s * 16 + (l4 << 2) + r;
          aout[p * AS + k] = f2bf(sigf(acc[s][q][r] + biass[k]));
        }
      }
    unsigned short* t2 = ain; ain = aout; aout = t2;
  }
  __syncthreads();
  // result in `ain` (= actB); copy to global u1bf[j][p][k]
#pragma unroll
  for (int c = tid; c < 1024; c += 256) {
    int p = c >> 4, k8 = (c & 15) << 3;
    uint4 v = *(const uint4*)&ain[p * AS + k8];
    *(uint4*)&u1bf[((size_t)j * MPTS + p) * WIDTH + k8] = v;
  }
}

// ------------- phase B: Gt2[j][p][m] = sig(dot128(wf[m][j], u1[j][:, p]) + bfin)
__global__ __launch_bounds__(256) void k_final(const float* __restrict__ wf,
                                               const float* __restrict__ bfin,
                                               const unsigned short* __restrict__ u1bf,
                                               unsigned short* __restrict__ Gt2) {
  constexpr int KP = 136;
  __shared__ unsigned short As[64 * KP];
  __shared__ unsigned short Bs[64 * KP];
  int bid = blockIdx.x;                    // 33*32
  int j = bid >> 5;
  int m0 = (bid & 31) << 6;
#pragma unroll
  for (int c = threadIdx.x; c < 64 * 32; c += 256) {
    int row = c >> 5, f4 = c & 31;
    float4 v = *(const float4*)(wf + ((size_t)(m0 + row) * WIN + j) * WIDTH + (f4 << 2));
    ushort4 h;
    h.x = f2bf(v.x); h.y = f2bf(v.y); h.z = f2bf(v.z); h.w = f2bf(v.w);
    *(ushort4*)(&As[row * KP + (f4 << 2)]) = h;
  }
#pragma unroll
  for (int c = threadIdx.x; c < 64 * 16; c += 256) {
    int p = c >> 4, ch = c & 15;
    uint4 v = *(const uint4*)(u1bf + (size_t)(j * MPTS + p) * WIDTH + (ch << 3));
    *(uint4*)(&Bs[p * KP + (ch << 3)]) = v;
  }
  __syncthreads();
  int wv = threadIdx.x >> 6, lane = threadIdx.x & 63;
  int l15 = lane & 15, l4 = lane >> 4;
  f32x4 acc[4] = {};
#pragma unroll
  for (int t = 0; t < 4; ++t) {
    int col = (t << 5) + (l4 << 3);
    bf16x8 a = *(const bf16x8*)(&As[(wv * 16 + l15) * KP + col]);
#pragma unroll
    for (int q = 0; q < 4; ++q) {
      bf16x8 bb = *(const bf16x8*)(&Bs[(q * 16 + l15) * KP + col]);
      acc[q] = __builtin_amdgcn_mfma_f32_16x16x32_bf16(a, bb, acc[q], 0, 0, 0);
    }
  }
#pragma unroll
  for (int q = 0; q < 4; ++q) {
    int mr = m0 + wv * 16 + (l4 << 2);
    int p = q * 16 + l15;
    float z0 = acc[q][0] + bfin[(size_t)(mr + 0) * WIN + j];
    float z1 = acc[q][1] + bfin[(size_t)(mr + 1) * WIN + j];
    float z2 = acc[q][2] + bfin[(size_t)(mr + 2) * WIN + j];
    float z3 = acc[q][3] + bfin[(size_t)(mr + 3) * WIN + j];
    ushort4 st;
    st.x = f2bf(sigf(z0)); st.y = f2bf(sigf(z1));
    st.z = f2bf(sigf(z2)); st.w = f2bf(sigf(z3));
    *(ushort4*)(&Gt2[(size_t)(j * MPTS + p) * MM + mr]) = st;
  }
}

// ------------- phase C: out[n,p] += sum_{j,m} xiT[n+j,m] * Gt2[j,p,m] ------
// grid 256 = 32 m-pairs x 8 n-tiles(256). ALL-j B resident in LDS (132KB,
// XOR-swizzled); barrier-free j-loop; acc persists across the 2 m-halves.
__global__ __launch_bounds__(256) void k_conv(const unsigned short* __restrict__ xiT,
                                              const unsigned short* __restrict__ Gt2,
                                              float* __restrict__ out) {
  extern __shared__ unsigned short lds[];
  unsigned short* Bs = lds;                // 33*64 rows x 32 shorts = 135168 B
  unsigned short* As = lds + 67584;        // 288 rows x 40 shorts  =  23040 B
  int bid = blockIdx.x;
  int mp = bid & 31;                       // m-pair
  int n0 = (bid >> 5) << 8;                // 8 n-tiles of 256
  int tid = threadIdx.x;
  int wv = tid >> 6, lane = tid & 63, l15 = lane & 15, l4 = lane >> 4;
  f32x4 acc[4][4] = {};
#pragma unroll
  for (int half = 0; half < 2; ++half) {
    int m0 = (mp << 6) + (half << 5);
    __syncthreads();                       // half=1: previous LDS reads done
    for (int c = tid; c < 1152; c += 256) {        // A: 288 rows x 4 uint4
      int row = c >> 2, g = c & 3;
      uint4 v = *(const uint4*)(xiT + (size_t)(n0 + row) * MM + m0 + (g << 3));
      *(uint4*)(&As[row * 40 + (g << 3)]) = v;
    }
    for (int c = tid; c < 8448; c += 256) {        // B: 33*64 rows x 4 uint4, swizzled
      int jp = c >> 2;                     // j*64 + p
      int p = jp & 63;
      int g = c & 3;
      uint4 v = *(const uint4*)(Gt2 + (size_t)jp * MM + m0 + (g << 3));
      int pg = g ^ (p & 3);
      *(uint4*)(&Bs[jp * 32 + (pg << 3)]) = v;
    }
    __syncthreads();
    for (int j = 0; j < WIN; ++j) {
      bf16x8 a[4], b[4];
#pragma unroll
      for (int s = 0; s < 4; ++s)
        a[s] = *(const bf16x8*)(&As[(wv * 64 + s * 16 + l15 + j) * 40 + (l4 << 3)]);
#pragma unroll
      for (int q = 0; q < 4; ++q) {
        int p = q * 16 + l15;
        b[q] = *(const bf16x8*)(&Bs[(j * 64 + p) * 32 + ((l4 ^ (p & 3)) << 3)]);
      }
#pragma unroll
      for (int s = 0; s < 4; ++s)
#pragma unroll
        for (int q = 0; q < 4; ++q)
          acc[s][q] = __builtin_amdgcn_mfma_f32_16x16x32_bf16(a[s], b[q], acc[s][q], 0, 0, 0);
    }
  }
#pragma unroll
  for (int s = 0; s < 4; ++s)
#pragma unroll
    for (int q = 0; q < 4; ++q) {
      int nr = n0 + wv * 64 + s * 16 + (l4 << 2);
      int p = q * 16 + l15;
#pragma unroll
      for (int i = 0; i < 4; ++i)
        atomicAdd(&out[(size_t)(nr + i) * MPTS + p], acc[s][q][i]);
    }
}

extern "C" void kernel_launch(void* const* d_in, const int* in_sizes, int n_in,
                              void* d_out, int out_size, void* d_ws, size_t ws_size,
                              hipStream_t stream) {
  const float* u    = (const float*)d_in[0];  // [64,64]
  const float* w0   = (const float*)d_in[1];  // [33,128,64]
  const float* b0   = (const float*)d_in[2];  // [33,128,1]
  const float* w    = (const float*)d_in[3];  // [2,33,128,128]
  const float* bias = (const float*)d_in[4];  // [2,33,128,1]
  const float* wf   = (const float*)d_in[5];  // [2048,33,128]
  const float* bfin = (const float*)d_in[6];  // [2048,33,1]
  const float* xi   = (const float*)d_in[7];  // [2048,2080]
  float* out = (float*)d_out;                 // [2048,64]
  char* ws = (char*)d_ws;
  unsigned short* xiT  = (unsigned short*)(ws);             // 8,519,680 B
  unsigned short* Gt2  = (unsigned short*)(ws + 8519680);   // 8,650,752 B
  unsigned short* u1bf = (unsigned short*)(ws + 17170432);  // 540,672 B

  hipFuncSetAttribute(reinterpret_cast<const void*>(&k_conv),
                      hipFuncAttributeMaxDynamicSharedMemorySize, 158208);

  hipMemsetAsync(out, 0, (size_t)out_size * sizeof(float), stream);
  k_transpose<<<dim3(65, 32), 256, 0, stream>>>(xi, xiT);
  k_mlp<<<WIN, 256, 0, stream>>>(u, w0, b0, w, bias, u1bf);
  k_final<<<33 * 32, 256, 0, stream>>>(wf, bfin, u1bf, Gt2);
  k_conv<<<256, 256, 158208, stream>>>(xiT, Gt2, out);   // <-- the R3 bug: was 0 dyn-LDS
}

// Round 5
// 180.933 us; speedup vs baseline: 1.1796x; 1.0238x over previous
//
#include <hip/hip_runtime.h>

#define WIN 33
#define WIDTH 128
#define MPTS 64
#define NN 2048
#define MM 2048
#define DD 64
#define NQ 2080   // N + 2L

typedef __bf16 bf16x8 __attribute__((ext_vector_type(8)));
typedef float f32x4 __attribute__((ext_vector_type(4)));

__device__ __forceinline__ unsigned short f2bf(float x) {
  union { float f; unsigned int u; } v; v.f = x;
  unsigned int r = v.u + 0x7FFFu + ((v.u >> 16) & 1u);  // RNE
  return (unsigned short)(r >> 16);
}
__device__ __forceinline__ float sigf(float x) { return 1.0f / (1.0f + __expf(-x)); }

// ------------- xi[M][NQ] f32  ->  xiT[NQ][M] bf16 (transpose + convert) ----
__global__ __launch_bounds__(256) void k_transpose(const float* __restrict__ xi,
                                                   unsigned short* __restrict__ xiT) {
  __shared__ float ts[64 * 37];
  int qb = blockIdx.x * 32;                // 65 tiles over NQ=2080
  int mb = blockIdx.y * 64;                // 32 tiles over M=2048
#pragma unroll
  for (int c = threadIdx.x; c < 512; c += 256) {   // 64 rows x 8 float4
    int row = c >> 3, c8 = c & 7;
    float4 v = *(const float4*)&xi[(size_t)(mb + row) * NQ + qb + (c8 << 2)];
    ts[row * 37 + (c8 << 2) + 0] = v.x;
    ts[row * 37 + (c8 << 2) + 1] = v.y;
    ts[row * 37 + (c8 << 2) + 2] = v.z;
    ts[row * 37 + (c8 << 2) + 3] = v.w;
  }
  __syncthreads();
#pragma unroll
  for (int c = threadIdx.x; c < 512; c += 256) {   // 32 q-rows x 16 m-quads
    int r = c >> 4, mq = c & 15;
    ushort4 h;
    h.x = f2bf(ts[(mq * 4 + 0) * 37 + r]);
    h.y = f2bf(ts[(mq * 4 + 1) * 37 + r]);
    h.z = f2bf(ts[(mq * 4 + 2) * 37 + r]);
    h.w = f2bf(ts[(mq * 4 + 3) * 37 + r]);
    *(ushort4*)&xiT[(size_t)(qb + r) * MM + mb + (mq << 2)] = h;
  }
}

// ------------- fused 3-layer MLP, one block per j -------------------------
__global__ __launch_bounds__(256) void k_mlp(const float* __restrict__ u,
                                             const float* __restrict__ w0,
                                             const float* __restrict__ b0,
                                             const float* __restrict__ w,
                                             const float* __restrict__ bias,
                                             unsigned short* __restrict__ u1bf) {
  constexpr int WS = 72;
  constexpr int AS = 136;
  __shared__ unsigned short ws[128 * WS];
  __shared__ unsigned short actA[64 * AS];
  __shared__ unsigned short actB[64 * AS];
  __shared__ float biass[128];
  int j = blockIdx.x;
  int tid = threadIdx.x;
  int wv = tid >> 6, lane = tid & 63, l15 = lane & 15, l4 = lane >> 4;

#pragma unroll
  for (int c = tid; c < 1024; c += 256) {
    int p = c >> 4, d4 = (c & 15) << 2;
    float4 v = *(const float4*)&u[(size_t)p * DD + d4];
    ushort4 h; h.x = f2bf(v.x); h.y = f2bf(v.y); h.z = f2bf(v.z); h.w = f2bf(v.w);
    *(ushort4*)&actA[p * AS + d4] = h;
  }
#pragma unroll
  for (int c = tid; c < 2048; c += 256) {
    int k = c >> 4, d4 = (c & 15) << 2;
    float4 v = *(const float4*)&w0[((size_t)j * 128 + k) * DD + d4];
    ushort4 h; h.x = f2bf(v.x); h.y = f2bf(v.y); h.z = f2bf(v.z); h.w = f2bf(v.w);
    *(ushort4*)&ws[k * WS + d4] = h;
  }
  if (tid < 128) biass[tid] = b0[j * 128 + tid];
  __syncthreads();

  {  // layer 0: K=64
    f32x4 acc[2][4] = {};
#pragma unroll
    for (int t = 0; t < 2; ++t) {
      int col = (t << 5) + (l4 << 3);
      bf16x8 a[2], b[4];
#pragma unroll
      for (int s = 0; s < 2; ++s)
        a[s] = *(const bf16x8*)&ws[(wv * 32 + s * 16 + l15) * WS + col];
#pragma unroll
      for (int q = 0; q < 4; ++q)
        b[q] = *(const bf16x8*)&actA[(q * 16 + l15) * AS + col];
#pragma unroll
      for (int s = 0; s < 2; ++s)
#pragma unroll
        for (int q = 0; q < 4; ++q)
          acc[s][q] = __builtin_amdgcn_mfma_f32_16x16x32_bf16(a[s], b[q], acc[s][q], 0, 0, 0);
    }
#pragma unroll
    for (int s = 0; s < 2; ++s)
#pragma unroll
      for (int q = 0; q < 4; ++q) {
        int p = q * 16 + l15;
#pragma unroll
        for (int r = 0; r < 4; ++r) {
          int k = wv * 32 + s * 16 + (l4 << 2) + r;
          actB[p * AS + k] = f2bf(sigf(acc[s][q][r] + biass[k]));
        }
      }
  }

  unsigned short* ain = actB;
  unsigned short* aout = actA;
#pragma unroll
  for (int i = 0; i < 2; ++i) {
    f32x4 acc[2][4] = {};
    const float* wbase = w + ((size_t)i * WIN + j) * 128 * 128;
#pragma unroll
    for (int h = 0; h < 2; ++h) {
      __syncthreads();
#pragma unroll
      for (int c = tid; c < 2048; c += 256) {
        int k = c >> 4, d4 = (c & 15) << 2;
        float4 v = *(const float4*)&wbase[(size_t)k * 128 + h * 64 + d4];
        ushort4 hh; hh.x = f2bf(v.x); hh.y = f2bf(v.y); hh.z = f2bf(v.z); hh.w = f2bf(v.w);
        *(ushort4*)&ws[k * WS + d4] = hh;
      }
      if (h == 0 && tid < 128) biass[tid] = bias[((size_t)i * WIN + j) * 128 + tid];
      __syncthreads();
#pragma unroll
      for (int t = 0; t < 2; ++t) {
        int col = (t << 5) + (l4 << 3);
        bf16x8 a[2], b[4];
#pragma unroll
        for (int s = 0; s < 2; ++s)
          a[s] = *(const bf16x8*)&ws[(wv * 32 + s * 16 + l15) * WS + col];
#pragma unroll
        for (int q = 0; q < 4; ++q)
          b[q] = *(const bf16x8*)&ain[(q * 16 + l15) * AS + h * 64 + col];
#pragma unroll
        for (int s = 0; s < 2; ++s)
#pragma unroll
          for (int q = 0; q < 4; ++q)
            acc[s][q] = __builtin_amdgcn_mfma_f32_16x16x32_bf16(a[s], b[q], acc[s][q], 0, 0, 0);
      }
    }
#pragma unroll
    for (int s = 0; s < 2; ++s)
#pragma unroll
      for (int q = 0; q < 4; ++q) {
        int p = q * 16 + l15;
#pragma unroll
        for (int r = 0; r < 4; ++r) {
          int k = wv * 32 + s * 16 + (l4 << 2) + r;
          aout[p * AS + k] = f2bf(sigf(acc[s][q][r] + biass[k]));
        }
      }
    unsigned short* t2 = ain; ain = aout; aout = t2;
  }
  __syncthreads();
#pragma unroll
  for (int c = tid; c < 1024; c += 256) {
    int p = c >> 4, k8 = (c & 15) << 3;
    uint4 v = *(const uint4*)&ain[p * AS + k8];
    *(uint4*)&u1bf[((size_t)j * MPTS + p) * WIDTH + k8] = v;
  }
}

// ------------- phase B: Gt2[j][p][m] = sig(dot128(wf[m][j], u1[j][:, p]) + bfin)
__global__ __launch_bounds__(256) void k_final(const float* __restrict__ wf,
                                               const float* __restrict__ bfin,
                                               const unsigned short* __restrict__ u1bf,
                                               unsigned short* __restrict__ Gt2) {
  constexpr int KP = 136;
  __shared__ unsigned short As[64 * KP];
  __shared__ unsigned short Bs[64 * KP];
  int bid = blockIdx.x;                    // 33*32
  int j = bid >> 5;
  int m0 = (bid & 31) << 6;
#pragma unroll
  for (int c = threadIdx.x; c < 64 * 32; c += 256) {
    int row = c >> 5, f4 = c & 31;
    float4 v = *(const float4*)(wf + ((size_t)(m0 + row) * WIN + j) * WIDTH + (f4 << 2));
    ushort4 h;
    h.x = f2bf(v.x); h.y = f2bf(v.y); h.z = f2bf(v.z); h.w = f2bf(v.w);
    *(ushort4*)(&As[row * KP + (f4 << 2)]) = h;
  }
#pragma unroll
  for (int c = threadIdx.x; c < 64 * 16; c += 256) {
    int p = c >> 4, ch = c & 15;
    uint4 v = *(const uint4*)(u1bf + (size_t)(j * MPTS + p) * WIDTH + (ch << 3));
    *(uint4*)(&Bs[p * KP + (ch << 3)]) = v;
  }
  __syncthreads();
  int wv = threadIdx.x >> 6, lane = threadIdx.x & 63;
  int l15 = lane & 15, l4 = lane >> 4;
  f32x4 acc[4] = {};
#pragma unroll
  for (int t = 0; t < 4; ++t) {
    int col = (t << 5) + (l4 << 3);
    bf16x8 a = *(const bf16x8*)(&As[(wv * 16 + l15) * KP + col]);
#pragma unroll
    for (int q = 0; q < 4; ++q) {
      bf16x8 bb = *(const bf16x8*)(&Bs[(q * 16 + l15) * KP + col]);
      acc[q] = __builtin_amdgcn_mfma_f32_16x16x32_bf16(a, bb, acc[q], 0, 0, 0);
    }
  }
#pragma unroll
  for (int q = 0; q < 4; ++q) {
    int mr = m0 + wv * 16 + (l4 << 2);
    int p = q * 16 + l15;
    float z0 = acc[q][0] + bfin[(size_t)(mr + 0) * WIN + j];
    float z1 = acc[q][1] + bfin[(size_t)(mr + 1) * WIN + j];
    float z2 = acc[q][2] + bfin[(size_t)(mr + 2) * WIN + j];
    float z3 = acc[q][3] + bfin[(size_t)(mr + 3) * WIN + j];
    ushort4 st;
    st.x = f2bf(sigf(z0)); st.y = f2bf(sigf(z1));
    st.z = f2bf(sigf(z2)); st.w = f2bf(sigf(z3));
    *(ushort4*)(&Gt2[(size_t)(j * MPTS + p) * MM + mr]) = st;
  }
}

// ------------- phase C: out[n,p] += sum_{j,m} xiT[n+j,m] * Gt2[j,p,m] ------
// grid 512 = 16 n-tiles(128) x 32 m-pairs(64 as 2 halves; split-K stays 32).
// 69.1 KB LDS -> 2 blocks/CU (2 waves/SIMD). B resident for 11 j per phase
// (3 phases). Register double-buffer prefetch of j+1 inside each phase.
// Wave-tile 32n x 64p: acc[2][4]; 6 ds_read_b128 + 8 MFMA per j.
__global__ __launch_bounds__(256) void k_conv(const unsigned short* __restrict__ xiT,
                                              const unsigned short* __restrict__ Gt2,
                                              float* __restrict__ out) {
  extern __shared__ unsigned short lds[];
  unsigned short* As = lds;                // 160 rows x 40 shorts = 12,800 B
  unsigned short* Bs = lds + 160 * 40;     // 704 rows (11j x 64p) x 40 = 56,320 B
  int bid = blockIdx.x;
  int n0 = (bid & 15) << 7;                // 16 n-tiles of 128
  int mp = bid >> 4;                       // 32 m-pairs
  int tid = threadIdx.x;
  int wv = tid >> 6, lane = tid & 63, l15 = lane & 15, l4 = lane >> 4;
  f32x4 acc[2][4] = {};
#pragma unroll
  for (int half = 0; half < 2; ++half) {
    int m0 = (mp << 6) + (half << 5);
    __syncthreads();                       // half=1: prior As/Bs reads done
    for (int c = tid; c < 640; c += 256) { // A: 160 rows x 4 uint4
      int row = c >> 2, g = c & 3;
      uint4 v = *(const uint4*)(xiT + (size_t)(n0 + row) * MM + m0 + (g << 3));
      *(uint4*)(&As[row * 40 + (g << 3)]) = v;
    }
    for (int ph = 0; ph < 3; ++ph) {
      int jb = ph * 11;
      if (ph) __syncthreads();             // prior Bs reads done
      for (int c = tid; c < 2816; c += 256) {      // B: 704 rows x 4 uint4
        int jp = c >> 2, g = c & 3;        // jp = jj*64 + p
        uint4 v = *(const uint4*)(Gt2 + ((size_t)(jb << 6) + jp) * MM + m0 + (g << 3));
        *(uint4*)(&Bs[jp * 40 + (g << 3)]) = v;
      }
      __syncthreads();
      bf16x8 a[2], b[4];
#pragma unroll
      for (int s = 0; s < 2; ++s)
        a[s] = *(const bf16x8*)(&As[(wv * 32 + s * 16 + l15 + jb) * 40 + (l4 << 3)]);
#pragma unroll
      for (int q = 0; q < 4; ++q)
        b[q] = *(const bf16x8*)(&Bs[(q * 16 + l15) * 40 + (l4 << 3)]);
#pragma unroll
      for (int jj = 0; jj < 11; ++jj) {
        bf16x8 an[2], bn[4];
        if (jj < 10) {                     // prefetch j+1 while computing j
#pragma unroll
          for (int s = 0; s < 2; ++s)
            an[s] = *(const bf16x8*)(&As[(wv * 32 + s * 16 + l15 + jb + jj + 1) * 40 + (l4 << 3)]);
#pragma unroll
          for (int q = 0; q < 4; ++q)
            bn[q] = *(const bf16x8*)(&Bs[((jj + 1) * 64 + q * 16 + l15) * 40 + (l4 << 3)]);
        }
#pragma unroll
        for (int s = 0; s < 2; ++s)
#pragma unroll
          for (int q = 0; q < 4; ++q)
            acc[s][q] = __builtin_amdgcn_mfma_f32_16x16x32_bf16(a[s], b[q], acc[s][q], 0, 0, 0);
#pragma unroll
        for (int s = 0; s < 2; ++s) a[s] = an[s];
#pragma unroll
        for (int q = 0; q < 4; ++q) b[q] = bn[q];
      }
    }
  }
#pragma unroll
  for (int s = 0; s < 2; ++s)
#pragma unroll
    for (int q = 0; q < 4; ++q) {
      int nr = n0 + wv * 32 + s * 16 + (l4 << 2);
      int p = q * 16 + l15;
#pragma unroll
      for (int i = 0; i < 4; ++i)
        atomicAdd(&out[(size_t)(nr + i) * MPTS + p], acc[s][q][i]);
    }
}

extern "C" void kernel_launch(void* const* d_in, const int* in_sizes, int n_in,
                              void* d_out, int out_size, void* d_ws, size_t ws_size,
                              hipStream_t stream) {
  const float* u    = (const float*)d_in[0];  // [64,64]
  const float* w0   = (const float*)d_in[1];  // [33,128,64]
  const float* b0   = (const float*)d_in[2];  // [33,128,1]
  const float* w    = (const float*)d_in[3];  // [2,33,128,128]
  const float* bias = (const float*)d_in[4];  // [2,33,128,1]
  const float* wf   = (const float*)d_in[5];  // [2048,33,128]
  const float* bfin = (const float*)d_in[6];  // [2048,33,1]
  const float* xi   = (const float*)d_in[7];  // [2048,2080]
  float* out = (float*)d_out;                 // [2048,64]
  char* ws = (char*)d_ws;
  unsigned short* xiT  = (unsigned short*)(ws);             // 8,519,680 B
  unsigned short* Gt2  = (unsigned short*)(ws + 8519680);   // 8,650,752 B
  unsigned short* u1bf = (unsigned short*)(ws + 17170432);  // 540,672 B

  hipFuncSetAttribute(reinterpret_cast<const void*>(&k_conv),
                      hipFuncAttributeMaxDynamicSharedMemorySize, 69120);

  hipMemsetAsync(out, 0, (size_t)out_size * sizeof(float), stream);
  k_transpose<<<dim3(65, 32), 256, 0, stream>>>(xi, xiT);
  k_mlp<<<WIN, 256, 0, stream>>>(u, w0, b0, w, bias, u1bf);
  k_final<<<33 * 32, 256, 0, stream>>>(wf, bfin, u1bf, Gt2);
  k_conv<<<512, 256, 69120, stream>>>(xiT, Gt2, out);
}